// Round 5
// baseline (283.252 us; speedup 1.0000x reference)
//
#include <hip/hip_runtime.h>
#include <hip/hip_bf16.h>

typedef __bf16 bf16_t;
typedef bf16_t bf16x8 __attribute__((ext_vector_type(8)));
typedef bf16_t bf16x4 __attribute__((ext_vector_type(4)));
typedef float  f32x4  __attribute__((ext_vector_type(4)));
typedef float  f32x8  __attribute__((ext_vector_type(8)));
typedef float  f32x16 __attribute__((ext_vector_type(16)));

#define B_  4
#define S_  2048
#define D_  1024
#define H_  16
#define HD  64

// 0.125 (d^-0.5) * log2(e): folded into q so QK^T score is the exp2 argument directly
#define QSCALE 0.1803368801111204f

// async global->LDS, 16B per lane, dst must be wave-uniform (HW adds lane*16)
__device__ __forceinline__ void async_copy16(const void* g, void* l) {
    __builtin_amdgcn_global_load_lds((const __attribute__((address_space(1))) void*)g,
                                     (__attribute__((address_space(3))) void*)l,
                                     16, 0, 0);
}

__device__ __forceinline__ float fast_exp2(float x) {
    float r;
    asm("v_exp_f32 %0, %1" : "=v"(r) : "v"(x));
    return r;
}

// ---------------- fp32 -> bf16 conversion ----------------
__global__ __launch_bounds__(256) void cvt_kernel(const float* __restrict__ in,
                                                  bf16_t* __restrict__ out, int n4) {
    int i = blockIdx.x * 256 + threadIdx.x;
    if (i >= n4) return;
    float4 f = ((const float4*)in)[i];
    bf16x4 o = { (bf16_t)f.x, (bf16_t)f.y, (bf16_t)f.z, (bf16_t)f.w };
    ((bf16x4*)out)[i] = o;
}

// ---------------- shared 128x128 GEMM tile core (A row-major MxK, Bt row-major NxK) ----------------
__device__ __forceinline__ void gemm_tile(const bf16_t* __restrict__ A,
                                          const bf16_t* __restrict__ Bt,
                                          int lda, int ldb, int m0, int n0, int K,
                                          bf16_t* As, bf16_t* Bs, f32x4 acc[4][4]) {
    const int lane = threadIdx.x & 63;
    const int wv   = threadIdx.x >> 6;
    const int wm   = wv >> 1, wn = wv & 1;
    const int r8   = lane >> 3, c8 = lane & 7;
    const int lo   = lane & 15, hi = lane >> 4;

    for (int k0 = 0; k0 < K; k0 += 64) {
        #pragma unroll
        for (int i = 0; i < 4; ++i) {
            const int c   = wv * 4 + i;       // chunk 0..15
            const int row = c * 8 + r8;       // tile row 0..127
            async_copy16(A  + (size_t)(m0 + row) * lda + k0 + c8 * 8, As + c * 512);
            async_copy16(Bt + (size_t)(n0 + row) * ldb + k0 + c8 * 8, Bs + c * 512);
        }
        __syncthreads();
        #pragma unroll
        for (int kk = 0; kk < 2; ++kk) {
            const int ko = kk * 32 + hi * 8;
            bf16x8 aF[4], bF[4];
            #pragma unroll
            for (int m = 0; m < 4; ++m)
                aF[m] = *(const bf16x8*)(As + (wm * 64 + m * 16 + lo) * 64 + ko);
            #pragma unroll
            for (int n = 0; n < 4; ++n)
                bF[n] = *(const bf16x8*)(Bs + (wn * 64 + n * 16 + lo) * 64 + ko);
            #pragma unroll
            for (int m = 0; m < 4; ++m)
                #pragma unroll
                for (int n = 0; n < 4; ++n)
                    acc[m][n] = __builtin_amdgcn_mfma_f32_16x16x32_bf16(aF[m], bF[n], acc[m][n], 0, 0, 0);
        }
        __syncthreads();
    }
}

// ---------------- GEMM 1: qkv = x @ w_qkv^T, epilogue scatters q/k/v ----------------
__global__ __launch_bounds__(256) void gemm_qkv_kernel(const bf16_t* __restrict__ A,
                                                       const bf16_t* __restrict__ Bt,
                                                       float* __restrict__ out,
                                                       bf16_t* __restrict__ q_ws,
                                                       bf16_t* __restrict__ k_ws) {
    __shared__ __align__(16) bf16_t As[128 * 64];
    __shared__ __align__(16) bf16_t Bs[128 * 64];
    const int m0 = blockIdx.y * 128, n0 = blockIdx.x * 128;
    const f32x4 zero = {0.f, 0.f, 0.f, 0.f};
    f32x4 acc[4][4];
    #pragma unroll
    for (int m = 0; m < 4; ++m)
        #pragma unroll
        for (int n = 0; n < 4; ++n) acc[m][n] = zero;

    gemm_tile(A, Bt, D_, D_, m0, n0, D_, As, Bs, acc);

    const int lane = threadIdx.x & 63, wv = threadIdx.x >> 6;
    const int wm = wv >> 1, wn = wv & 1;
    const int lo = lane & 15, hi = lane >> 4;
    #pragma unroll
    for (int m = 0; m < 4; ++m) {
        #pragma unroll
        for (int n = 0; n < 4; ++n) {
            const int gcol = n0 + wn * 64 + n * 16 + lo;     // 0..3071
            const int sec  = gcol >> 10;                     // 0=q 1=k 2=v
            const int e    = gcol & 1023;
            const int h    = e >> 6, dv = e & 63;
            #pragma unroll
            for (int j = 0; j < 4; ++j) {
                const int grow = m0 + wm * 64 + m * 16 + hi * 4 + j;  // b*S+s
                const float v  = acc[m][n][j];
                const int b = grow >> 11, s = grow & 2047;
                const size_t idx = ((((size_t)b * H_ + h) * S_ + s) << 6) + dv;
                if (sec == 0) {
                    q_ws[idx] = (bf16_t)(v * QSCALE);  // scale folded into q
                } else if (sec == 1) {
                    out[8388608u + idx] = v;      // k fp32 output
                    k_ws[idx] = (bf16_t)v;
                } else {
                    out[16777216u + idx] = v;     // v fp32 output
                }
            }
        }
    }
}

// ---------------- transpose v (fp32 (B,H,S,64)) -> Vt bf16 (B,H,64,S) ----------------
__global__ __launch_bounds__(256) void transpose_v_kernel(const float* __restrict__ v_f32,
                                                          bf16_t* __restrict__ vt) {
    __shared__ __align__(16) bf16_t T[64][72];
    const int bh = blockIdx.x;
    const int s0 = blockIdx.y * 64;
    const int t  = threadIdx.x;
    {
        const int sl  = t >> 2;
        const int dv0 = (t & 3) * 16;
        const float* src = v_f32 + ((size_t)bh * S_ + s0 + sl) * HD + dv0;
        float tmp[16];
        #pragma unroll
        for (int i = 0; i < 4; ++i) *(float4*)(tmp + i * 4) = ((const float4*)src)[i];
        #pragma unroll
        for (int i = 0; i < 16; ++i) T[dv0 + i][sl] = (bf16_t)tmp[i];
    }
    __syncthreads();
    {
        const int dv = t >> 2;
        const int sc = (t & 3) * 16;
        bf16x8 o0 = *(const bf16x8*)&T[dv][sc];
        bf16x8 o1 = *(const bf16x8*)&T[dv][sc + 8];
        bf16x8* dst = (bf16x8*)(vt + ((size_t)bh * HD + dv) * S_ + s0 + sc);
        dst[0] = o0;
        dst[1] = o1;
    }
}

// ---------------- flash attention (causal), wave-independent, 32x32 MFMA, no KV LDS ----------------
// One wave per (bh, qblock): 4096 waves. Per-wave body identical to the verified round-3 code
// (single acc chain, sequential tiles). All 4 waves of a block share bh (same K/V addresses ->
// L1/L2 reuse) and take 4 consecutive qblocks; heavy-first dispatch; XCD-pinned bh.
__global__ __launch_bounds__(256) void attn_kernel(const bf16_t* __restrict__ q_ws,
                                                   const bf16_t* __restrict__ k_ws,
                                                   const bf16_t* __restrict__ vt_ws,
                                                   bf16_t* __restrict__ attn_ws) {
    __shared__ __align__(16) bf16_t T[4][32][72];   // per-wave epilogue transpose buffer
    const int lane = threadIdx.x & 63;
    const int wv   = threadIdx.x >> 6;
    // blk: [x:3 | r:7], bh = x + 8*(r&7) (all waves same bh), qblock = 63 - ((r>>3)*4 + wv)
    const int blk = blockIdx.x;                     // 0..1023
    const int x   = blk & 7;
    const int r   = blk >> 3;                       // 0..127
    const int bh  = x + 8 * (r & 7);                // 0..63, XCD-pinned via x
    const int qblock = 63 - ((r >> 3) * 4 + wv);    // heavy blocks dispatched first
    const int q0  = qblock * 32;

    const int ql = lane & 31;       // q column (and d row for PV tiles)
    const int hb = lane >> 5;
    const size_t kv_base = (size_t)bh * (S_ * HD);  // q_ws,k_ws: (B,H,S,64)
    const size_t vt_base = (size_t)bh * (HD * S_);  // vt: (B,H,64,S)
    const int b = bh >> 4, h = bh & 15;

    const bf16_t* kbase  = k_ws  + kv_base + (size_t)ql * HD + hb * 8;
    const bf16_t* vbase0 = vt_ws + vt_base + (size_t)ql * S_        + hb * 8;
    const bf16_t* vbase1 = vt_ws + vt_base + (size_t)(32 + ql) * S_ + hb * 8;

    // Q fragment (B-operand of QK): lane holds Q[q0+ql][16c + hb*8 + j], pre-scaled
    bf16x8 qF[4];
    const bf16_t* qrow = q_ws + kv_base + (size_t)(q0 + ql) * HD + hb * 8;
    #pragma unroll
    for (int c = 0; c < 4; ++c) qF[c] = *(const bf16x8*)(qrow + 16 * c);

    f32x16 accT0 = {}, accT1 = {};  // out^T d-tiles (d0=0,32): col=q, row=d_local
    float lsum = 0.f;               // local-half softmax denominator

    auto tile_step = [&](int key0, bool diag) {
        // --- S^T = K · Q^T : C[key][q], col=q=ql, row=key_local ---
        f32x16 s = {};
        const bf16_t* kr = kbase + (size_t)key0 * HD;
        #pragma unroll
        for (int c = 0; c < 4; ++c) {
            bf16x8 kF = *(const bf16x8*)(kr + 16 * c);
            s = __builtin_amdgcn_mfma_f32_32x32x16_bf16(kF, qF[c], s, 0, 0, 0);
        }
        if (diag) {
            #pragma unroll
            for (int rr = 0; rr < 16; ++rr) {
                const int kloc = (rr & 3) + 8 * (rr >> 2) + 4 * hb;
                if (kloc > ql) s[rr] = -1e30f;
            }
        }
        // --- P = exp2(s) (scale+log2e pre-folded into q) ---
        #pragma unroll
        for (int rr = 0; rr < 16; ++rr) s[rr] = fast_exp2(s[rr]);
        // --- local-half sum (packed tree) ---
        f32x8 t8 = __builtin_shufflevector(s, s, 0, 1, 2, 3, 4, 5, 6, 7) +
                   __builtin_shufflevector(s, s, 8, 9, 10, 11, 12, 13, 14, 15);
        f32x4 t4 = __builtin_shufflevector(t8, t8, 0, 1, 2, 3) +
                   __builtin_shufflevector(t8, t8, 4, 5, 6, 7);
        lsum += (t4[0] + t4[1]) + (t4[2] + t4[3]);

        // --- pack P^T to bf16 PV B-fragments: 8 cvt_pk + 4 permlane32_swap ---
        unsigned w[8];
        #pragma unroll
        for (int i = 0; i < 8; ++i) {
            unsigned d;
            asm("v_cvt_pk_bf16_f32 %0, %1, %2" : "=v"(d) : "v"(s[2 * i]), "v"(s[2 * i + 1]));
            w[i] = d;
        }
        union { unsigned u[4]; bf16x8 v; } pf0, pf1;
        {
            auto r0 = __builtin_amdgcn_permlane32_swap(w[0], w[2], false, false);
            auto r1 = __builtin_amdgcn_permlane32_swap(w[1], w[3], false, false);
            pf0.u[0] = r0[0]; pf0.u[1] = r1[0]; pf0.u[2] = r0[1]; pf0.u[3] = r1[1];
        }
        {
            auto r0 = __builtin_amdgcn_permlane32_swap(w[4], w[6], false, false);
            auto r1 = __builtin_amdgcn_permlane32_swap(w[5], w[7], false, false);
            pf1.u[0] = r0[0]; pf1.u[1] = r1[0]; pf1.u[2] = r0[1]; pf1.u[3] = r1[1];
        }

        // --- out^T += V^T · P^T : 4 mfma ---
        bf16x8 vF00 = *(const bf16x8*)(vbase0 + key0);
        bf16x8 vF10 = *(const bf16x8*)(vbase1 + key0);
        bf16x8 vF01 = *(const bf16x8*)(vbase0 + key0 + 16);
        bf16x8 vF11 = *(const bf16x8*)(vbase1 + key0 + 16);
        accT0 = __builtin_amdgcn_mfma_f32_32x32x16_bf16(vF00, pf0.v, accT0, 0, 0, 0);
        accT1 = __builtin_amdgcn_mfma_f32_32x32x16_bf16(vF10, pf0.v, accT1, 0, 0, 0);
        accT0 = __builtin_amdgcn_mfma_f32_32x32x16_bf16(vF01, pf1.v, accT0, 0, 0, 0);
        accT1 = __builtin_amdgcn_mfma_f32_32x32x16_bf16(vF11, pf1.v, accT1, 0, 0, 0);
    };

    for (int t = 0; t < qblock; ++t) tile_step(t * 32, false);
    tile_step(q0, true);   // diagonal tile

    const float ltot = lsum + __shfl_xor(lsum, 32, 64);
    const float inv  = 1.0f / ltot;

    // --- epilogue: normalize, transpose via per-wave LDS, coalesced store ---
    #pragma unroll
    for (int rr = 0; rr < 16; ++rr) {
        const int dl = (rr & 3) + 8 * (rr >> 2) + 4 * hb;
        T[wv][ql][dl]      = (bf16_t)(accT0[rr] * inv);
        T[wv][ql][32 + dl] = (bf16_t)(accT1[rr] * inv);
    }
    asm volatile("s_waitcnt lgkmcnt(0)" ::: "memory");
    #pragma unroll
    for (int it = 0; it < 4; ++it) {
        const int ch  = it * 64 + lane;
        const int row = ch >> 3, c8 = ch & 7;
        bf16x8 o = *(const bf16x8*)&T[wv][row][c8 * 8];
        *(bf16x8*)(attn_ws + ((size_t)(b * S_ + q0 + row)) * D_ + h * HD + c8 * 8) = o;
    }
}

// ---------------- GEMM 2: out = attn_ws @ w_out^T (fp32 store) ----------------
__global__ __launch_bounds__(256) void gemm_out_kernel(const bf16_t* __restrict__ A,
                                                       const bf16_t* __restrict__ Bt,
                                                       float* __restrict__ out) {
    __shared__ __align__(16) bf16_t As[128 * 64];
    __shared__ __align__(16) bf16_t Bs[128 * 64];
    const int m0 = blockIdx.y * 128, n0 = blockIdx.x * 128;
    const f32x4 zero = {0.f, 0.f, 0.f, 0.f};
    f32x4 acc[4][4];
    #pragma unroll
    for (int m = 0; m < 4; ++m)
        #pragma unroll
        for (int n = 0; n < 4; ++n) acc[m][n] = zero;

    gemm_tile(A, Bt, D_, D_, m0, n0, D_, As, Bs, acc);

    const int lane = threadIdx.x & 63, wv = threadIdx.x >> 6;
    const int wm = wv >> 1, wn = wv & 1;
    const int lo = lane & 15, hi = lane >> 4;
    #pragma unroll
    for (int m = 0; m < 4; ++m) {
        #pragma unroll
        for (int n = 0; n < 4; ++n) {
            const int gcol = n0 + wn * 64 + n * 16 + lo;
            #pragma unroll
            for (int j = 0; j < 4; ++j) {
                const int grow = m0 + wm * 64 + m * 16 + hi * 4 + j;
                out[(size_t)grow * D_ + gcol] = acc[m][n][j];
            }
        }
    }
}

extern "C" void kernel_launch(void* const* d_in, const int* in_sizes, int n_in,
                              void* d_out, int out_size, void* d_ws, size_t ws_size,
                              hipStream_t stream) {
    (void)in_sizes; (void)n_in; (void)out_size; (void)ws_size;
    const float* x     = (const float*)d_in[0];
    // d_in[1] = mask (known causal, unused)
    const float* w_qkv = (const float*)d_in[2];
    const float* w_out = (const float*)d_in[3];
    float* out = (float*)d_out;
    char* ws = (char*)d_ws;

    bf16_t* x_bf    = (bf16_t*)(ws);                 // 16,777,216 B
    bf16_t* wqkv_bf = (bf16_t*)(ws + 16777216);      //  6,291,456 B
    bf16_t* wout_bf = (bf16_t*)(ws + 23068672);      //  2,097,152 B
    bf16_t* q_ws    = (bf16_t*)(ws + 25165824);      // 16,777,216 B
    bf16_t* k_ws    = (bf16_t*)(ws + 41943040);      // 16,777,216 B
    bf16_t* vt_ws   = (bf16_t*)(ws + 58720256);      // 16,777,216 B
    bf16_t* attn_ws = (bf16_t*)(ws + 75497472);      // 16,777,216 B  (total 92,274,688)

    cvt_kernel<<<8192, 256, 0, stream>>>(x, x_bf, 2097152);
    cvt_kernel<<<3072, 256, 0, stream>>>(w_qkv, wqkv_bf, 786432);
    cvt_kernel<<<1024, 256, 0, stream>>>(w_out, wout_bf, 262144);

    gemm_qkv_kernel<<<dim3(24, 64), 256, 0, stream>>>(x_bf, wqkv_bf, out, q_ws, k_ws);
    transpose_v_kernel<<<dim3(64, 32), 256, 0, stream>>>(out + 16777216, vt_ws);
    attn_kernel<<<1024, 256, 0, stream>>>(q_ws, k_ws, vt_ws, attn_ws);
    gemm_out_kernel<<<dim3(8, 64), 256, 0, stream>>>(attn_ws, wout_bf, out);
}

// Round 6
// 263.715 us; speedup vs baseline: 1.0741x; 1.0741x over previous
//
#include <hip/hip_runtime.h>
#include <hip/hip_bf16.h>

typedef __bf16 bf16_t;
typedef bf16_t bf16x8 __attribute__((ext_vector_type(8)));
typedef bf16_t bf16x4 __attribute__((ext_vector_type(4)));
typedef float  f32x4  __attribute__((ext_vector_type(4)));
typedef float  f32x8  __attribute__((ext_vector_type(8)));
typedef float  f32x16 __attribute__((ext_vector_type(16)));

#define B_  4
#define S_  2048
#define D_  1024
#define H_  16
#define HD  64

// 0.125 (d^-0.5) * log2(e): folded into q so QK^T score is the exp2 argument directly
#define QSCALE 0.1803368801111204f

// async global->LDS, 16B per lane, dst must be wave-uniform (HW adds lane*16)
__device__ __forceinline__ void async_copy16(const void* g, void* l) {
    __builtin_amdgcn_global_load_lds((const __attribute__((address_space(1))) void*)g,
                                     (__attribute__((address_space(3))) void*)l,
                                     16, 0, 0);
}

__device__ __forceinline__ float fast_exp2(float x) {
    float r;
    asm("v_exp_f32 %0, %1" : "=v"(r) : "v"(x));
    return r;
}

// ---------------- fp32 -> bf16 conversion ----------------
__global__ __launch_bounds__(256) void cvt_kernel(const float* __restrict__ in,
                                                  bf16_t* __restrict__ out, int n4) {
    int i = blockIdx.x * 256 + threadIdx.x;
    if (i >= n4) return;
    float4 f = ((const float4*)in)[i];
    bf16x4 o = { (bf16_t)f.x, (bf16_t)f.y, (bf16_t)f.z, (bf16_t)f.w };
    ((bf16x4*)out)[i] = o;
}

// ---------------- shared 128x128 GEMM tile core (A row-major MxK, Bt row-major NxK) ----------------
__device__ __forceinline__ void gemm_tile(const bf16_t* __restrict__ A,
                                          const bf16_t* __restrict__ Bt,
                                          int lda, int ldb, int m0, int n0, int K,
                                          bf16_t* As, bf16_t* Bs, f32x4 acc[4][4]) {
    const int lane = threadIdx.x & 63;
    const int wv   = threadIdx.x >> 6;
    const int wm   = wv >> 1, wn = wv & 1;
    const int r8   = lane >> 3, c8 = lane & 7;
    const int lo   = lane & 15, hi = lane >> 4;

    for (int k0 = 0; k0 < K; k0 += 64) {
        #pragma unroll
        for (int i = 0; i < 4; ++i) {
            const int c   = wv * 4 + i;       // chunk 0..15
            const int row = c * 8 + r8;       // tile row 0..127
            async_copy16(A  + (size_t)(m0 + row) * lda + k0 + c8 * 8, As + c * 512);
            async_copy16(Bt + (size_t)(n0 + row) * ldb + k0 + c8 * 8, Bs + c * 512);
        }
        __syncthreads();
        #pragma unroll
        for (int kk = 0; kk < 2; ++kk) {
            const int ko = kk * 32 + hi * 8;
            bf16x8 aF[4], bF[4];
            #pragma unroll
            for (int m = 0; m < 4; ++m)
                aF[m] = *(const bf16x8*)(As + (wm * 64 + m * 16 + lo) * 64 + ko);
            #pragma unroll
            for (int n = 0; n < 4; ++n)
                bF[n] = *(const bf16x8*)(Bs + (wn * 64 + n * 16 + lo) * 64 + ko);
            #pragma unroll
            for (int m = 0; m < 4; ++m)
                #pragma unroll
                for (int n = 0; n < 4; ++n)
                    acc[m][n] = __builtin_amdgcn_mfma_f32_16x16x32_bf16(aF[m], bF[n], acc[m][n], 0, 0, 0);
        }
        __syncthreads();
    }
}

// ---------------- GEMM 1: qkv = x @ w_qkv^T, epilogue scatters q/k/v ----------------
__global__ __launch_bounds__(256) void gemm_qkv_kernel(const bf16_t* __restrict__ A,
                                                       const bf16_t* __restrict__ Bt,
                                                       float* __restrict__ out,
                                                       bf16_t* __restrict__ q_ws,
                                                       bf16_t* __restrict__ k_ws) {
    __shared__ __align__(16) bf16_t As[128 * 64];
    __shared__ __align__(16) bf16_t Bs[128 * 64];
    const int m0 = blockIdx.y * 128, n0 = blockIdx.x * 128;
    const f32x4 zero = {0.f, 0.f, 0.f, 0.f};
    f32x4 acc[4][4];
    #pragma unroll
    for (int m = 0; m < 4; ++m)
        #pragma unroll
        for (int n = 0; n < 4; ++n) acc[m][n] = zero;

    gemm_tile(A, Bt, D_, D_, m0, n0, D_, As, Bs, acc);

    const int lane = threadIdx.x & 63, wv = threadIdx.x >> 6;
    const int wm = wv >> 1, wn = wv & 1;
    const int lo = lane & 15, hi = lane >> 4;
    #pragma unroll
    for (int m = 0; m < 4; ++m) {
        #pragma unroll
        for (int n = 0; n < 4; ++n) {
            const int gcol = n0 + wn * 64 + n * 16 + lo;     // 0..3071
            const int sec  = gcol >> 10;                     // 0=q 1=k 2=v
            const int e    = gcol & 1023;
            const int h    = e >> 6, dv = e & 63;
            #pragma unroll
            for (int j = 0; j < 4; ++j) {
                const int grow = m0 + wm * 64 + m * 16 + hi * 4 + j;  // b*S+s
                const float v  = acc[m][n][j];
                const int b = grow >> 11, s = grow & 2047;
                const size_t idx = ((((size_t)b * H_ + h) * S_ + s) << 6) + dv;
                if (sec == 0) {
                    q_ws[idx] = (bf16_t)(v * QSCALE);  // scale folded into q
                } else if (sec == 1) {
                    out[8388608u + idx] = v;      // k fp32 output
                    k_ws[idx] = (bf16_t)v;
                } else {
                    out[16777216u + idx] = v;     // v fp32 output
                }
            }
        }
    }
}

// ---------------- transpose v (fp32 (B,H,S,64)) -> Vt bf16 (B,H,64,S) ----------------
__global__ __launch_bounds__(256) void transpose_v_kernel(const float* __restrict__ v_f32,
                                                          bf16_t* __restrict__ vt) {
    __shared__ __align__(16) bf16_t T[64][72];
    const int bh = blockIdx.x;
    const int s0 = blockIdx.y * 64;
    const int t  = threadIdx.x;
    {
        const int sl  = t >> 2;
        const int dv0 = (t & 3) * 16;
        const float* src = v_f32 + ((size_t)bh * S_ + s0 + sl) * HD + dv0;
        float tmp[16];
        #pragma unroll
        for (int i = 0; i < 4; ++i) *(float4*)(tmp + i * 4) = ((const float4*)src)[i];
        #pragma unroll
        for (int i = 0; i < 16; ++i) T[dv0 + i][sl] = (bf16_t)tmp[i];
    }
    __syncthreads();
    {
        const int dv = t >> 2;
        const int sc = (t & 3) * 16;
        bf16x8 o0 = *(const bf16x8*)&T[dv][sc];
        bf16x8 o1 = *(const bf16x8*)&T[dv][sc + 8];
        bf16x8* dst = (bf16x8*)(vt + ((size_t)bh * HD + dv) * S_ + s0 + sc);
        dst[0] = o0;
        dst[1] = o1;
    }
}

// ---------------- flash attention (causal), wave-independent, 32x32 MFMA, no KV LDS ----------------
// Round-3 uniform pair structure (wave pair handles qblocks (p, 63-p)) + 2-way KEY SPLIT:
// waves (2j, 2j+1) of a block compute key-halves of the same pair; unnormalized acc + partial
// denominators merge exactly via LDS: out = (acc0+acc1)/(l0+l1). 4096 uniform ~32.5-tile waves.
__global__ __launch_bounds__(256) void attn_kernel(const bf16_t* __restrict__ q_ws,
                                                   const bf16_t* __restrict__ k_ws,
                                                   const bf16_t* __restrict__ vt_ws,
                                                   bf16_t* __restrict__ attn_ws) {
    __shared__ __align__(16) float MRG[2][2][64][16];   // [pair][acc0/1][lane][16] merge buffer
    __shared__ float LSUM[2][64];
    __shared__ __align__(16) bf16_t T[2][32][72];       // per-pair epilogue transpose buffer
    const int lane = threadIdx.x & 63;
    const int wv   = threadIdx.x >> 6;
    // blk: [x:3 | r:7]; bh = x + 8*(r&7) (all waves same bh); pair p = (r>>3)*2 + (wv>>1)
    const int blk   = blockIdx.x;                   // 0..1023
    const int x     = blk & 7;
    const int r     = blk >> 3;                     // 0..127
    const int bh    = x + 8 * (r & 7);              // 0..63, XCD-pinned via x
    const int pr    = wv >> 1;                      // pair slot in block (0/1)
    const int khalf = wv & 1;                       // key half (0 = low, 1 = high+diag)
    const int p     = (r >> 3) * 2 + pr;            // 0..31

    const int ql = lane & 31;       // q column (and d row for PV tiles)
    const int hb = lane >> 5;
    const size_t kv_base = (size_t)bh * (S_ * HD);  // q_ws,k_ws: (B,H,S,64)
    const size_t vt_base = (size_t)bh * (HD * S_);  // vt: (B,H,64,S)
    const int b = bh >> 4, h = bh & 15;

    const bf16_t* kbase  = k_ws  + kv_base + (size_t)ql * HD + hb * 8;
    const bf16_t* vbase0 = vt_ws + vt_base + (size_t)ql * S_        + hb * 8;
    const bf16_t* vbase1 = vt_ws + vt_base + (size_t)(32 + ql) * S_ + hb * 8;

    #pragma unroll 1
    for (int pass = 0; pass < 2; ++pass) {
        const int qblock = pass ? (63 - p) : p;
        const int q0 = qblock * 32;
        const int nt  = qblock + 1;                 // tiles incl diagonal
        const int mid = nt >> 1;
        const int tstart = khalf ? mid : 0;
        const int tend   = khalf ? nt  : mid;

        // Q fragment (B-operand of QK): lane holds Q[q0+ql][16c + hb*8 + j], pre-scaled
        bf16x8 qF[4];
        const bf16_t* qrow = q_ws + kv_base + (size_t)(q0 + ql) * HD + hb * 8;
        #pragma unroll
        for (int c = 0; c < 4; ++c) qF[c] = *(const bf16x8*)(qrow + 16 * c);

        f32x16 accT0 = {}, accT1 = {};  // out^T d-tiles (d0=0,32): col=q, row=d_local
        float lsum = 0.f;               // partial (this key-half, this lane-half) denominator

        for (int t = tstart; t < tend; ++t) {
            const int key0 = t * 32;
            const bool diag = (t == qblock);
            // --- S^T = K · Q^T : C[key][q], col=q=ql, row=key_local ---
            f32x16 s = {};
            const bf16_t* kr = kbase + (size_t)key0 * HD;
            #pragma unroll
            for (int c = 0; c < 4; ++c) {
                bf16x8 kF = *(const bf16x8*)(kr + 16 * c);
                s = __builtin_amdgcn_mfma_f32_32x32x16_bf16(kF, qF[c], s, 0, 0, 0);
            }
            if (diag) {
                #pragma unroll
                for (int rr = 0; rr < 16; ++rr) {
                    const int kloc = (rr & 3) + 8 * (rr >> 2) + 4 * hb;
                    if (kloc > ql) s[rr] = -1e30f;
                }
            }
            // --- P = exp2(s) (scale+log2e pre-folded into q) ---
            #pragma unroll
            for (int rr = 0; rr < 16; ++rr) s[rr] = fast_exp2(s[rr]);
            // --- local-half sum (packed tree) ---
            f32x8 t8 = __builtin_shufflevector(s, s, 0, 1, 2, 3, 4, 5, 6, 7) +
                       __builtin_shufflevector(s, s, 8, 9, 10, 11, 12, 13, 14, 15);
            f32x4 t4 = __builtin_shufflevector(t8, t8, 0, 1, 2, 3) +
                       __builtin_shufflevector(t8, t8, 4, 5, 6, 7);
            lsum += (t4[0] + t4[1]) + (t4[2] + t4[3]);

            // --- pack P^T to bf16 PV B-fragments: 8 cvt_pk + 4 permlane32_swap ---
            unsigned w[8];
            #pragma unroll
            for (int i = 0; i < 8; ++i) {
                unsigned d;
                asm("v_cvt_pk_bf16_f32 %0, %1, %2" : "=v"(d) : "v"(s[2 * i]), "v"(s[2 * i + 1]));
                w[i] = d;
            }
            union { unsigned u[4]; bf16x8 v; } pf0, pf1;
            {
                auto r0 = __builtin_amdgcn_permlane32_swap(w[0], w[2], false, false);
                auto r1 = __builtin_amdgcn_permlane32_swap(w[1], w[3], false, false);
                pf0.u[0] = r0[0]; pf0.u[1] = r1[0]; pf0.u[2] = r0[1]; pf0.u[3] = r1[1];
            }
            {
                auto r0 = __builtin_amdgcn_permlane32_swap(w[4], w[6], false, false);
                auto r1 = __builtin_amdgcn_permlane32_swap(w[5], w[7], false, false);
                pf1.u[0] = r0[0]; pf1.u[1] = r1[0]; pf1.u[2] = r0[1]; pf1.u[3] = r1[1];
            }

            // --- out^T += V^T · P^T : 4 mfma ---
            bf16x8 vF00 = *(const bf16x8*)(vbase0 + key0);
            bf16x8 vF10 = *(const bf16x8*)(vbase1 + key0);
            bf16x8 vF01 = *(const bf16x8*)(vbase0 + key0 + 16);
            bf16x8 vF11 = *(const bf16x8*)(vbase1 + key0 + 16);
            accT0 = __builtin_amdgcn_mfma_f32_32x32x16_bf16(vF00, pf0.v, accT0, 0, 0, 0);
            accT1 = __builtin_amdgcn_mfma_f32_32x32x16_bf16(vF10, pf0.v, accT1, 0, 0, 0);
            accT0 = __builtin_amdgcn_mfma_f32_32x32x16_bf16(vF01, pf1.v, accT0, 0, 0, 0);
            accT1 = __builtin_amdgcn_mfma_f32_32x32x16_bf16(vF11, pf1.v, accT1, 0, 0, 0);
        }

        // --- key-split merge: khalf1 -> LDS, khalf0 adds, normalizes, stores ---
        if (khalf) {
            *(f32x16*)&MRG[pr][0][lane][0] = accT0;
            *(f32x16*)&MRG[pr][1][lane][0] = accT1;
            LSUM[pr][lane] = lsum;
        }
        __syncthreads();
        if (!khalf) {
            accT0 += *(const f32x16*)&MRG[pr][0][lane][0];
            accT1 += *(const f32x16*)&MRG[pr][1][lane][0];
            lsum  += LSUM[pr][lane];
            const float ltot = lsum + __shfl_xor(lsum, 32, 64);
            const float inv  = 1.0f / ltot;
            #pragma unroll
            for (int rr = 0; rr < 16; ++rr) {
                const int dl = (rr & 3) + 8 * (rr >> 2) + 4 * hb;
                T[pr][ql][dl]      = (bf16_t)(accT0[rr] * inv);
                T[pr][ql][32 + dl] = (bf16_t)(accT1[rr] * inv);
            }
            asm volatile("s_waitcnt lgkmcnt(0)" ::: "memory");
            #pragma unroll
            for (int it = 0; it < 4; ++it) {
                const int ch  = it * 64 + lane;
                const int row = ch >> 3, c8 = ch & 7;
                bf16x8 o = *(const bf16x8*)&T[pr][row][c8 * 8];
                *(bf16x8*)(attn_ws + ((size_t)(b * S_ + q0 + row)) * D_ + h * HD + c8 * 8) = o;
            }
        }
        __syncthreads();   // LDS safe to reuse next pass
    }
}

// ---------------- GEMM 2: out = attn_ws @ w_out^T (fp32 store) ----------------
__global__ __launch_bounds__(256) void gemm_out_kernel(const bf16_t* __restrict__ A,
                                                       const bf16_t* __restrict__ Bt,
                                                       float* __restrict__ out) {
    __shared__ __align__(16) bf16_t As[128 * 64];
    __shared__ __align__(16) bf16_t Bs[128 * 64];
    const int m0 = blockIdx.y * 128, n0 = blockIdx.x * 128;
    const f32x4 zero = {0.f, 0.f, 0.f, 0.f};
    f32x4 acc[4][4];
    #pragma unroll
    for (int m = 0; m < 4; ++m)
        #pragma unroll
        for (int n = 0; n < 4; ++n) acc[m][n] = zero;

    gemm_tile(A, Bt, D_, D_, m0, n0, D_, As, Bs, acc);

    const int lane = threadIdx.x & 63, wv = threadIdx.x >> 6;
    const int wm = wv >> 1, wn = wv & 1;
    const int lo = lane & 15, hi = lane >> 4;
    #pragma unroll
    for (int m = 0; m < 4; ++m) {
        #pragma unroll
        for (int n = 0; n < 4; ++n) {
            const int gcol = n0 + wn * 64 + n * 16 + lo;
            #pragma unroll
            for (int j = 0; j < 4; ++j) {
                const int grow = m0 + wm * 64 + m * 16 + hi * 4 + j;
                out[(size_t)grow * D_ + gcol] = acc[m][n][j];
            }
        }
    }
}

extern "C" void kernel_launch(void* const* d_in, const int* in_sizes, int n_in,
                              void* d_out, int out_size, void* d_ws, size_t ws_size,
                              hipStream_t stream) {
    (void)in_sizes; (void)n_in; (void)out_size; (void)ws_size;
    const float* x     = (const float*)d_in[0];
    // d_in[1] = mask (known causal, unused)
    const float* w_qkv = (const float*)d_in[2];
    const float* w_out = (const float*)d_in[3];
    float* out = (float*)d_out;
    char* ws = (char*)d_ws;

    bf16_t* x_bf    = (bf16_t*)(ws);                 // 16,777,216 B
    bf16_t* wqkv_bf = (bf16_t*)(ws + 16777216);      //  6,291,456 B
    bf16_t* wout_bf = (bf16_t*)(ws + 23068672);      //  2,097,152 B
    bf16_t* q_ws    = (bf16_t*)(ws + 25165824);      // 16,777,216 B
    bf16_t* k_ws    = (bf16_t*)(ws + 41943040);      // 16,777,216 B
    bf16_t* vt_ws   = (bf16_t*)(ws + 58720256);      // 16,777,216 B
    bf16_t* attn_ws = (bf16_t*)(ws + 75497472);      // 16,777,216 B  (total 92,274,688)

    cvt_kernel<<<8192, 256, 0, stream>>>(x, x_bf, 2097152);
    cvt_kernel<<<3072, 256, 0, stream>>>(w_qkv, wqkv_bf, 786432);
    cvt_kernel<<<1024, 256, 0, stream>>>(w_out, wout_bf, 262144);

    gemm_qkv_kernel<<<dim3(24, 64), 256, 0, stream>>>(x_bf, wqkv_bf, out, q_ws, k_ws);
    transpose_v_kernel<<<dim3(64, 32), 256, 0, stream>>>(out + 16777216, vt_ws);
    attn_kernel<<<1024, 256, 0, stream>>>(q_ws, k_ws, vt_ws, attn_ws);
    gemm_out_kernel<<<dim3(8, 64), 256, 0, stream>>>(attn_ws, wout_bf, out);
}